// Round 5
// baseline (133.521 us; speedup 1.0000x reference)
//
#include <hip/hip_runtime.h>

// AdaptiveConv: out[b,c,h,w] = sum_{idx<25} x[b,c,h+idx/5, w+idx%5] * kernel[b,idx,h,w]
// Shapes: x (8,64,260,260) f32, kernel (8,25,256,256) f32, out (8,64,256,256) f32.
//
// R4 structure: latency-bound fix (R3 was 21% occupancy, 68 VGPR w/ spilled taps).
//  - ROWS=2 output rows per thread -> kk[2][25]=50 floats fits registers for real.
//  - x rows streamed 5 floats at a time (live window ~57 floats total).
//  - channel dim split 2-way across grid.z -> 2048 blocks (8/CU of work).
//  - __launch_bounds__(256,4): 128-VGPR cap, 4 waves/EU = 50% occupancy target.

constexpr int K  = 5;
constexpr int B  = 8;
constexpr int C  = 64;
constexpr int H  = 256;
constexpr int W  = 256;
constexpr int HX = H + K - 1;   // 260
constexpr int WX = W + K - 1;   // 260

constexpr int ROWS   = 2;       // output rows per thread
constexpr int CSPLIT = 2;       // channel split across grid.z
constexpr int CPB    = C / CSPLIT;

__global__ __launch_bounds__(256, 4)
void adaptive_conv_kernel(const float* __restrict__ x,
                          const float* __restrict__ kern,
                          float* __restrict__ out) {
    const int w  = threadIdx.x;           // 0..255, coalesced axis
    const int h0 = blockIdx.x * ROWS;     // 0..254
    const int b  = blockIdx.y;            // 0..7
    const int c0 = blockIdx.z * CPB;      // 0 or 32

    // ---- kernel taps for my 2 output pixels -> registers (read once/block) ----
    float kk[ROWS][K * K];
    {
        const float* kb = kern + (size_t)b * (K * K * H * W) + (size_t)h0 * W + w;
        #pragma unroll
        for (int idx = 0; idx < K * K; ++idx) {
            #pragma unroll
            for (int r = 0; r < ROWS; ++r) {
                kk[r][idx] = kb[(size_t)idx * (H * W) + r * W];
            }
        }
    }

    const float* xb = x   + ((size_t)b * C + c0) * (HX * WX) + (size_t)h0 * WX + w;
    float*       ob = out + ((size_t)b * C + c0) * (H * W)   + (size_t)h0 * W  + w;

    for (int c = 0; c < CPB; ++c) {
        const float* xc = xb + (size_t)c * (HX * WX);

        float acc[ROWS];
        #pragma unroll
        for (int r = 0; r < ROWS; ++r) acc[r] = 0.0f;

        // Stream x rows t = 0..ROWS+K-2; row t feeds acc[r] with tap row i = t-r.
        #pragma unroll
        for (int t = 0; t < ROWS + K - 1; ++t) {
            float xr[K];
            #pragma unroll
            for (int j = 0; j < K; ++j) {
                xr[j] = xc[t * WX + j];   // coalesced across lanes; j-shifts hit L1
            }
            #pragma unroll
            for (int r = 0; r < ROWS; ++r) {
                const int i = t - r;
                if (i >= 0 && i < K) {
                    #pragma unroll
                    for (int j = 0; j < K; ++j) {
                        acc[r] = fmaf(xr[j], kk[r][i * K + j], acc[r]);
                    }
                }
            }
        }

        float* oc = ob + (size_t)c * (H * W);
        #pragma unroll
        for (int r = 0; r < ROWS; ++r) {
            // out written once, never read: keep it out of the caches.
            __builtin_nontemporal_store(acc[r], oc + r * W);
        }
    }
}

extern "C" void kernel_launch(void* const* d_in, const int* in_sizes, int n_in,
                              void* d_out, int out_size, void* d_ws, size_t ws_size,
                              hipStream_t stream) {
    const float* x    = (const float*)d_in[0];
    const float* kern = (const float*)d_in[1];
    float*       out  = (float*)d_out;

    dim3 grid(H / ROWS, B, CSPLIT);   // 128 x 8 x 2 = 2048 blocks
    dim3 block(W);                    // 256 threads, one per output column
    adaptive_conv_kernel<<<grid, block, 0, stream>>>(x, kern, out);
}

// Round 6
// 133.190 us; speedup vs baseline: 1.0025x; 1.0025x over previous
//
#include <hip/hip_runtime.h>

// AdaptiveConv: out[b,c,h,w] = sum_{idx<25} x[b,c,h+idx/5, w+idx%5] * kernel[b,idx,h,w]
// Shapes: x (8,64,260,260) f32, kernel (8,25,256,256) f32, out (8,64,256,256) f32.
//
// R5: R4 showed hipcc sinks loop-invariant tap loads back into the channel loop
// (VGPR=32, FETCH +94MB, latency-bound at 10% VALUBusy). Fixes:
//  - taps PINNED in VGPRs via asm volatile("" : "+v") — opaque output cannot be
//    rematerialized or sunk, so the 50 tap values stay register-resident across
//    all 32 channel iterations.
//  - x row loads vectorized: dword-aligned float4 + 1 scalar (2 loads/row vs 5).
//  - CSPLIT=2 kept: 2048 blocks = 8/CU of work; tap double-read served by L3.

constexpr int K  = 5;
constexpr int B  = 8;
constexpr int C  = 64;
constexpr int H  = 256;
constexpr int W  = 256;
constexpr int HX = H + K - 1;   // 260
constexpr int WX = W + K - 1;   // 260

constexpr int ROWS   = 2;       // output rows per thread -> kk[2][25] = 50 pinned VGPRs
constexpr int CSPLIT = 2;       // channel split across grid.z
constexpr int CPB    = C / CSPLIT;

typedef float f4 __attribute__((ext_vector_type(4)));
// 4-byte-aligned float4 view: lane addresses are only dword-aligned (base+w*4).
struct __attribute__((packed, aligned(4))) f4u { f4 v; };

__global__ __launch_bounds__(256, 4)
void adaptive_conv_kernel(const float* __restrict__ x,
                          const float* __restrict__ kern,
                          float* __restrict__ out) {
    const int w  = threadIdx.x;           // 0..255, coalesced axis
    const int h0 = blockIdx.x * ROWS;     // output row pair
    const int b  = blockIdx.y;            // 0..7
    const int c0 = blockIdx.z * CPB;      // 0 or 32

    // ---- kernel taps for my 2 output pixels -> registers (read once/block) ----
    float kk[ROWS][K * K];
    {
        const float* kb = kern + (size_t)b * (K * K * H * W) + (size_t)h0 * W + w;
        #pragma unroll
        for (int idx = 0; idx < K * K; ++idx) {
            #pragma unroll
            for (int r = 0; r < ROWS; ++r) {
                kk[r][idx] = kb[(size_t)idx * (H * W) + r * W];
            }
        }
    }
    // Pin all 50 taps in VGPRs: an asm output is opaque — the compiler cannot
    // sink the loads into the channel loop or rematerialize them (R4's failure).
    #pragma unroll
    for (int idx = 0; idx < K * K; ++idx) {
        #pragma unroll
        for (int r = 0; r < ROWS; ++r) {
            asm volatile("" : "+v"(kk[r][idx]));
        }
    }

    const float* xb = x   + ((size_t)b * C + c0) * (HX * WX) + (size_t)h0 * WX + w;
    float*       ob = out + ((size_t)b * C + c0) * (H * W)   + (size_t)h0 * W  + w;

    for (int c = 0; c < CPB; ++c) {
        const float* xc = xb + (size_t)c * (HX * WX);

        float acc[ROWS];
        #pragma unroll
        for (int r = 0; r < ROWS; ++r) acc[r] = 0.0f;

        // Stream x rows t = 0..5; row t feeds acc[r] with tap row i = t-r.
        #pragma unroll
        for (int t = 0; t < ROWS + K - 1; ++t) {
            // x[w .. w+4] at row t: one dword-aligned dwordx4 + one scalar.
            f4    xq = ((const f4u*)(xc + t * WX))->v;
            float x4 = xc[t * WX + 4];
            float xr[K] = {xq.x, xq.y, xq.z, xq.w, x4};
            #pragma unroll
            for (int r = 0; r < ROWS; ++r) {
                const int i = t - r;
                if (0 <= i && i < K) {
                    #pragma unroll
                    for (int j = 0; j < K; ++j) {
                        acc[r] = fmaf(xr[j], kk[r][i * K + j], acc[r]);
                    }
                }
            }
        }

        float* oc = ob + (size_t)c * (H * W);
        #pragma unroll
        for (int r = 0; r < ROWS; ++r) {
            // out written once, never read: keep it out of the caches.
            __builtin_nontemporal_store(acc[r], oc + r * W);
        }
    }
}

extern "C" void kernel_launch(void* const* d_in, const int* in_sizes, int n_in,
                              void* d_out, int out_size, void* d_ws, size_t ws_size,
                              hipStream_t stream) {
    const float* x    = (const float*)d_in[0];
    const float* kern = (const float*)d_in[1];
    float*       out  = (float*)d_out;

    dim3 grid(H / ROWS, B, CSPLIT);   // 128 x 8 x 2 = 2048 blocks
    dim3 block(W);                    // 256 threads, one per output column
    adaptive_conv_kernel<<<grid, block, 0, stream>>>(x, kern, out);
}